// Round 6
// baseline (1379.465 us; speedup 1.0000x reference)
//
#include <hip/hip_runtime.h>
#include <hip/hip_bf16.h>
#include <stdint.h>

typedef __attribute__((ext_vector_type(8))) short s16x8;
typedef __attribute__((ext_vector_type(4))) float f32x4;

#define D_DIM 2048
#define V_DIM 32768
#define M_DIM 4096
#define N_SEQ 2048
#define K_TOP 64
#define NSLOT 512   // 128 v-tiles * 4 wc
#define EBCAP 512   // entries per 256x256 tile (avg ~130)

// ---------- helpers ----------
static __device__ __forceinline__ float bf2f(unsigned short u) {
  union { unsigned int i; float f; } v; v.i = ((unsigned int)u) << 16; return v.f;
}
static __device__ __forceinline__ unsigned int pack2_bf16(float lo, float hi) {
  unsigned int ul = __float_as_uint(lo), uh = __float_as_uint(hi);
  ul = (ul + 0x7FFFu + ((ul >> 16) & 1u)) >> 16;        // RNE
  uh = (uh + 0x7FFFu + ((uh >> 16) & 1u)) >> 16;
  return ul | (uh << 16);
}
typedef __attribute__((address_space(3))) unsigned int lds_u32_t;
typedef const __attribute__((address_space(1))) unsigned int glb_u32_t;
static __device__ __forceinline__ void gload16(const void* g, void* l) {
  __builtin_amdgcn_global_load_lds((glb_u32_t*)g, (lds_u32_t*)l, 16, 0, 0);
}

// ---------- cast f32 -> bf16 (both tensors, one launch) ----------
__global__ void cast_bf16_kernel(const float4* __restrict__ inA, uint4* __restrict__ outA, int nA8,
                                 const float4* __restrict__ inB, uint4* __restrict__ outB, int nB8) {
  int i = blockIdx.x * blockDim.x + threadIdx.x;
  int stride = gridDim.x * blockDim.x;
  int tot = nA8 + nB8;
  for (; i < tot; i += stride) {
    const float4* in = (i < nA8) ? inA : inB;
    uint4* out = (i < nA8) ? outA : outB;
    int j = (i < nA8) ? i : i - nA8;
    float4 a = in[2 * j], b = in[2 * j + 1];
    uint4 r;
    r.x = pack2_bf16(a.x, a.y);
    r.y = pack2_bf16(a.z, a.w);
    r.z = pack2_bf16(b.x, b.y);
    r.w = pack2_bf16(b.z, b.w);
    out[j] = r;
  }
}

// ---------- binning: (m, id) -> per-(mt,vt)-tile entry lists ----------
__global__ __launch_bounds__(256) void bin_kernel(
    const int* __restrict__ tids, const int* __restrict__ tlab,
    unsigned int* __restrict__ cnt, unsigned int* __restrict__ ebuf) {
  int idx = blockIdx.x * 256 + threadIdx.x;
  if (idx >= M_DIM * (K_TOP + 1)) return;
  int m = idx / (K_TOP + 1), k = idx - m * (K_TOP + 1);
  int id;
  if (k < K_TOP) id = tids[m * K_TOP + k];
  else {
    int n = m & (N_SEQ - 1);
    if (n == N_SEQ - 1) return;   // no gold for last position
    id = tlab[m + 1];
  }
  int tile = ((m >> 8) << 7) + (id >> 8);   // mt*128 + vt
  unsigned int pos = atomicAdd(&cnt[tile], 1u);
  if (pos < EBCAP)
    ebuf[tile * EBCAP + pos] =
        ((unsigned int)k << 16) | ((unsigned int)(m & 255) << 8) | (unsigned int)(id & 255);
}

// ---------- fat-phase GEMM: A direct global->reg, B-only LDS dbuf ----------
// BM=BN=256, BK=32, 8 waves (2M x 4N), per-wave 128x64 out, acc[8][4].
// Per K-tile body: {A(T+1)->regs (8 ld) + stage B(T+1) (2 gload_lds);
//                   vmcnt(10); BAR; 4 ds_read; 32 MFMA; BAR}
// B LDS swizzle: granule' = kqg ^ (row&3) ^ ((row>>2)&3), pre-applied on src.

#define BAR do { __builtin_amdgcn_s_barrier(); asm volatile("" ::: "memory"); } while (0)
#define VMC(N) asm volatile("s_waitcnt vmcnt(" #N ")" ::: "memory")
#define PRIO1 __builtin_amdgcn_s_setprio(1)
#define PRIO0 __builtin_amdgcn_s_setprio(0)

#define BODY(ACUR, ANXT, BUF, NVM, DOLOAD) do { \
  if (DOLOAD) { \
    _Pragma("unroll") \
    for (int mi = 0; mi < 8; ++mi) \
      ANXT[mi] = *(const s16x8*)(xbf + abase + mi * 32768u + koff); \
    const unsigned short* bs_ = bsrc + koff; \
    gload16(bs_, ldst_b + (((BUF) ^ 1) << 14)); \
    gload16(bs_ + 128u * D_DIM, ldst_b + (((BUF) ^ 1) << 14) + 8192); \
    koff += 32; \
  } \
  if (NVM) { VMC(10); } else { VMC(0); } \
  BAR; \
  _Pragma("unroll") \
  for (int ni = 0; ni < 4; ++ni) \
    bfrag[ni] = *(const s16x8*)(bfr_base + ((BUF) << 14) + ni * 1024); \
  PRIO1; \
  _Pragma("unroll") \
  for (int mi = 0; mi < 8; ++mi) { \
    _Pragma("unroll") \
    for (int ni = 0; ni < 4; ++ni) \
      acc[mi][ni] = __builtin_amdgcn_mfma_f32_16x16x32_bf16(ACUR[mi], bfrag[ni], acc[mi][ni], 0, 0, 0); \
  } \
  PRIO0; \
  BAR; \
} while (0)

__global__ __launch_bounds__(512, 2) void gemm_lse_kernel(
    const unsigned short* __restrict__ xbf,   // [M_DIM][D_DIM]
    const unsigned short* __restrict__ wbf,   // [V_DIM][D_DIM]
    float* __restrict__ pMax,                 // [M_DIM][NSLOT]
    float* __restrict__ pSum,
    const unsigned int* __restrict__ bcnt,    // [2048]
    const unsigned int* __restrict__ ebuf,    // [2048][EBCAP]
    float* __restrict__ gout) {               // [M_DIM][K_TOP+1]
  __shared__ __align__(16) char lds[131072];  // B dbuf in first 32KB; epilogue reuses all

  // mt-pinned XCD map: each XCD owns 2 mt rows (x slice 2MB -> L2-resident),
  // streams vt. W is L3-resident (128MB bf16).
  const int bid0 = blockIdx.x;
  const int xcd = bid0 & 7, idx = bid0 >> 3;
  const int mt = xcd * 2 + (idx & 1);
  const int vt = idx >> 1;
  const int tid = threadIdx.x, lane = tid & 63, w = tid >> 6;
  const int wr = w >> 2, wc = w & 3;
  const int fr = lane & 15, kqg = lane >> 4;
  const int brow = wc * 64;

  // A direct-load base: row = mt*256 + wr*128 + mi*16 + fr, k = kqg*8 + koff
  const unsigned int abase = (unsigned int)(mt * 256 + wr * 128 + fr) * D_DIM + kqg * 8;

  // B staging: thread t -> LDS row t>>2 (issue0) / +128 (issue1), granule t&3.
  // src granule pre-swizzled: (t&3) ^ ((t>>2)&3) ^ ((t>>4)&3)
  const int sgr = ((tid & 3) ^ ((tid >> 2) & 3) ^ ((tid >> 4) & 3)) << 3;
  const unsigned short* bsrc = wbf + (size_t)(vt * 256 + (tid >> 2)) * D_DIM + sgr;
  char* ldst_b = lds + tid * 16;

  // B fragment read base: row = brow + ni*16 + fr (byte row*64),
  // granule' = kqg ^ (fr&3) ^ ((fr>>2)&3)  (row-derived terms reduce to fr-only)
  const char* bfr_base = lds + (unsigned int)((brow + fr) * 64 +
                         ((kqg ^ (fr & 3) ^ ((fr >> 2) & 3)) << 4));

  f32x4 acc[8][4];
#pragma unroll
  for (int i = 0; i < 8; i++)
#pragma unroll
    for (int j = 0; j < 4; j++) acc[i][j] = (f32x4){0.f, 0.f, 0.f, 0.f};

  s16x8 aA[8], aB[8], bfrag[4];

  // prologue: A(0)->aA, stage B(0)->buf0, drain
#pragma unroll
  for (int mi = 0; mi < 8; ++mi)
    aA[mi] = *(const s16x8*)(xbf + abase + mi * 32768u);
  gload16(bsrc, ldst_b);
  gload16(bsrc + 128u * D_DIM, ldst_b + 8192);
  VMC(0);
  BAR;

  unsigned int koff = 32;

  // 64 K-tiles, unrolled x2 for A reg ping-pong
  for (int it = 0; it < 31; ++it) {
    BODY(aA, aB, 0, 1, 1);
    BODY(aB, aA, 1, 1, 1);
  }
  BODY(aA, aB, 0, 1, 1);   // tile 62 (loads tile 63)
  BODY(aB, aA, 1, 0, 0);   // tile 63 (tail)

  // ---- epilogue A: per-row (max, sumexp) over this wave's 64-col slice ----
  const int slot = vt * 4 + wc;
#pragma unroll
  for (int mi = 0; mi < 8; mi++) {
#pragma unroll
    for (int j = 0; j < 4; j++) {
      const int row = mt * 256 + wr * 128 + mi * 16 + kqg * 4 + j;
      float v0 = acc[mi][0][j], v1 = acc[mi][1][j];
      float v2 = acc[mi][2][j], v3 = acc[mi][3][j];
      float mx = fmaxf(fmaxf(v0, v1), fmaxf(v2, v3));
      for (int s = 1; s < 16; s <<= 1) mx = fmaxf(mx, __shfl_xor(mx, s));
      float sm = __expf(v0 - mx) + __expf(v1 - mx) +
                 __expf(v2 - mx) + __expf(v3 - mx);
      for (int s = 1; s < 16; s <<= 1) sm += __shfl_xor(sm, s);
      if (fr == 0) {
        pMax[row * NSLOT + slot] = mx;
        pSum[row * NSLOT + slot] = sm;
      }
    }
  }

  // ---- epilogue B: fused gather of requested logits via LDS round-trip ----
  const int tile = (mt << 7) + vt;
  unsigned int cn = bcnt[tile];
  if (cn > EBCAP) cn = EBCAP;
  const unsigned int* elist = ebuf + tile * EBCAP;
  float* ldsf = (float*)lds;

  __syncthreads();
#pragma unroll
  for (int half = 0; half < 2; ++half) {
    if (wr == half) {
#pragma unroll
      for (int mi = 0; mi < 8; mi++) {
        const int r0 = mi * 16 + kqg * 4;
        const int cs = (kqg & 1) << 4;
#pragma unroll
        for (int ni = 0; ni < 4; ni++) {
          const int c0 = (wc * 64 + ni * 16 + fr) ^ cs;
#pragma unroll
          for (int j = 0; j < 4; j++)
            ldsf[(r0 + j) * 256 + c0] = acc[mi][ni][j];
        }
      }
    }
    __syncthreads();
    for (unsigned int e = tid; e < cn; e += 512) {
      unsigned int u = elist[e];
      int r = (u >> 8) & 255;
      if ((r >> 7) == half) {
        int c = u & 255, k = u >> 16;
        int rl = r & 127;
        gout[(mt * 256 + r) * (K_TOP + 1) + k] = ldsf[rl * 256 + (c ^ (((rl >> 2) & 1) << 4))];
      }
    }
    __syncthreads();
  }
}

// ---------- final: lse merge + CE + KD, atomic into scalar ----------
__global__ __launch_bounds__(256) void reduce_kernel(
    const float* __restrict__ pMax, const float* __restrict__ pSum,
    const float* __restrict__ gout, const float* __restrict__ t_lp,
    const int* __restrict__ t_mask, float* __restrict__ out) {
  const int tid = threadIdx.x, lane = tid & 63, w = tid >> 6;
  const int m = blockIdx.x * 4 + w;

  float msl[8], ssl[8];
  float M = -1e30f;
#pragma unroll
  for (int j = 0; j < 8; j++) {
    msl[j] = pMax[m * NSLOT + lane + j * 64];
    ssl[j] = pSum[m * NSLOT + lane + j * 64];
    M = fmaxf(M, msl[j]);
  }
  for (int s = 1; s < 64; s <<= 1) M = fmaxf(M, __shfl_xor(M, s));
  float S = 0.f;
#pragma unroll
  for (int j = 0; j < 8; j++) S += ssl[j] * __expf(msl[j] - M);
  for (int s = 1; s < 64; s <<= 1) S += __shfl_xor(S, s);
  const float lse = M + logf(S);

  const int n = m & (N_SEQ - 1);
  float ce = 0.f;
  if (n < N_SEQ - 1) ce = lse - gout[m * (K_TOP + 1) + K_TOP];

  const float g = gout[m * (K_TOP + 1) + lane];
  float gM = g;
  for (int s = 1; s < 64; s <<= 1) gM = fmaxf(gM, __shfl_xor(gM, s));
  float gE = __expf(g - gM);
  float gS = gE;
  for (int s = 1; s < 64; s <<= 1) gS += __shfl_xor(gS, s);
  const float lseK = gM + logf(gS);

  const float tl = t_lp[m * K_TOP + lane];
  const int mk = t_mask[m * K_TOP + lane];
  float kd = mk ? __expf(tl) * (tl - (g - lseK)) : 0.f;
  for (int s = 1; s < 64; s <<= 1) kd += __shfl_xor(kd, s);

  if (lane == 0) atomicAdd(out, 0.5f * kd + 0.5f * ce);
}

// ---------- launch ----------
extern "C" void kernel_launch(void* const* d_in, const int* in_sizes, int n_in,
                              void* d_out, int out_size, void* d_ws, size_t ws_size,
                              hipStream_t stream) {
  const float* x   = (const float*)d_in[0];   // [2,2048,2048]
  const float* Wm  = (const float*)d_in[1];   // [32768,2048]
  const int* tids  = (const int*)d_in[2];     // [2,2048,64]
  const float* tlp = (const float*)d_in[3];   // [2,2048,64]
  const int* tmask = (const int*)d_in[4];     // [2,2048,64]
  const int* tlab  = (const int*)d_in[5];     // [2,2048]
  float* out = (float*)d_out;

  char* ws = (char*)d_ws;
  unsigned short* wbf = (unsigned short*)ws;                                 // 128 MB
  unsigned short* xbf = (unsigned short*)(ws + (size_t)V_DIM * D_DIM * 2);   // 16 MB
  char* p = ws + (size_t)V_DIM * D_DIM * 2 + (size_t)M_DIM * D_DIM * 2;
  float* pMax = (float*)p;                       p += (size_t)M_DIM * NSLOT * 4;
  float* pSum = (float*)p;                       p += (size_t)M_DIM * NSLOT * 4;
  float* gout = (float*)p;                       p += (size_t)M_DIM * (K_TOP + 1) * 4;
  unsigned int* bcnt = (unsigned int*)p;         p += 2048 * 4;
  unsigned int* ebuf = (unsigned int*)p;         p += (size_t)2048 * EBCAP * 4;

  hipMemsetAsync(d_out, 0, sizeof(float), stream);
  hipMemsetAsync(bcnt, 0, 2048 * 4, stream);

  bin_kernel<<<(M_DIM * (K_TOP + 1) + 255) / 256, 256, 0, stream>>>(
      tids, tlab, bcnt, ebuf);

  cast_bf16_kernel<<<8192, 256, 0, stream>>>(
      (const float4*)Wm, (uint4*)wbf, (V_DIM * D_DIM) / 8,
      (const float4*)x, (uint4*)xbf, (M_DIM * D_DIM) / 8);

  gemm_lse_kernel<<<(M_DIM / 256) * (V_DIM / 256), 512, 0, stream>>>(
      xbf, wbf, pMax, pSum, bcnt, ebuf, gout);

  reduce_kernel<<<M_DIM / 4, 256, 0, stream>>>(pMax, pSum, gout, tlp, tmask, out);
}

// Round 7
// 825.123 us; speedup vs baseline: 1.6718x; 1.6718x over previous
//
#include <hip/hip_runtime.h>
#include <hip/hip_bf16.h>
#include <stdint.h>

typedef __attribute__((ext_vector_type(8))) short s16x8;
typedef __attribute__((ext_vector_type(16))) float f32x16;

#define D_DIM 2048
#define V_DIM 32768
#define M_DIM 4096
#define N_SEQ 2048
#define K_TOP 64
#define NSLOT 512   // 128 v-tiles * 4 wc
#define EBCAP 512   // entries per 256x256 tile (avg ~130)

// ---------- helpers ----------
static __device__ __forceinline__ float bf2f(unsigned short u) {
  union { unsigned int i; float f; } v; v.i = ((unsigned int)u) << 16; return v.f;
}
static __device__ __forceinline__ unsigned int pack2_bf16(float lo, float hi) {
  unsigned int ul = __float_as_uint(lo), uh = __float_as_uint(hi);
  ul = (ul + 0x7FFFu + ((ul >> 16) & 1u)) >> 16;        // RNE
  uh = (uh + 0x7FFFu + ((uh >> 16) & 1u)) >> 16;
  return ul | (uh << 16);
}
typedef __attribute__((address_space(3))) unsigned int lds_u32_t;
typedef const __attribute__((address_space(1))) unsigned int glb_u32_t;
static __device__ __forceinline__ void gload16(const void* g, void* l) {
  __builtin_amdgcn_global_load_lds((glb_u32_t*)g, (lds_u32_t*)l, 16, 0, 0);
}

// ---------- cast f32 -> bf16 (both tensors, one launch) ----------
__global__ void cast_bf16_kernel(const float4* __restrict__ inA, uint4* __restrict__ outA, int nA8,
                                 const float4* __restrict__ inB, uint4* __restrict__ outB, int nB8) {
  int i = blockIdx.x * blockDim.x + threadIdx.x;
  int stride = gridDim.x * blockDim.x;
  int tot = nA8 + nB8;
  for (; i < tot; i += stride) {
    const float4* in = (i < nA8) ? inA : inB;
    uint4* out = (i < nA8) ? outA : outB;
    int j = (i < nA8) ? i : i - nA8;
    float4 a = in[2 * j], b = in[2 * j + 1];
    uint4 r;
    r.x = pack2_bf16(a.x, a.y);
    r.y = pack2_bf16(a.z, a.w);
    r.z = pack2_bf16(b.x, b.y);
    r.w = pack2_bf16(b.z, b.w);
    out[j] = r;
  }
}

// ---------- binning: (m, id) -> per-(mt,vt)-tile entry lists ----------
__global__ __launch_bounds__(256) void bin_kernel(
    const int* __restrict__ tids, const int* __restrict__ tlab,
    unsigned int* __restrict__ cnt, unsigned int* __restrict__ ebuf) {
  int idx = blockIdx.x * 256 + threadIdx.x;
  if (idx >= M_DIM * (K_TOP + 1)) return;
  int m = idx / (K_TOP + 1), k = idx - m * (K_TOP + 1);
  int id;
  if (k < K_TOP) id = tids[m * K_TOP + k];
  else {
    int n = m & (N_SEQ - 1);
    if (n == N_SEQ - 1) return;   // no gold for last position
    id = tlab[m + 1];
  }
  int tile = ((m >> 8) << 7) + (id >> 8);   // mt*128 + vt
  unsigned int pos = atomicAdd(&cnt[tile], 1u);
  if (pos < EBCAP)
    ebuf[tile * EBCAP + pos] =
        ((unsigned int)k << 16) | ((unsigned int)(m & 255) << 8) | (unsigned int)(id & 255);
}

// ---------- 256x256 GEMM, 32x32x16 MFMA, 2 fat phases per BK=64 tile ----------
// 8 waves (2M x 4N), per-wave 128x64 out = 4mi x 2ni frags of 32x32, acc f32x16[4][2].
// LDS: 128KB dbuf, halves pos0=B[0:128) pos1=B[128:256) pos2=A[0:128) pos3=A[128:256).
// Row = 128B; granule swizzle g ^= row&7 (pre-applied on global src). Conflict-free
// (16-lane b128 subgroups: 8 granules x 2 lanes = 2-way = free).
// A frag (mi,kk): row=mi*32+(lane&31), granule 2kk+(lane>>5). B same with W-row=out-col.
// Reads: B(T) + A kk0/kk1 read at T-1 P_B; A kk2/kk3 read at T P_A. All consumed
// one barrier after read. Stages: P_A: halves 4T+7,4T+8; P_B: 4T+9,4T+10, vmcnt(6).

#define BAR do { __builtin_amdgcn_s_barrier(); asm volatile("" ::: "memory"); } while (0)
#define VMC(N) asm volatile("s_waitcnt vmcnt(" #N ")" ::: "memory")
#define PRIO1 __builtin_amdgcn_s_setprio(1)
#define PRIO0 __builtin_amdgcn_s_setprio(0)

#define LDFRAG(BASE, R, G) \
  (*(const s16x8*)((BASE) + (R) * 128 + ((((G)) ^ ((R) & 7)) << 4)))
#define LDA32(BASE, MI, KK) LDFRAG(BASE, (MI) * 32 + l31, 2 * (KK) + hi)
#define LDB32(BASE, NI, KK) LDFRAG(BASE, browB + (NI) * 32 + l31, 2 * (KK) + hi)

#define STAGE(H) do { \
  int tt_ = (H) >> 2, pos_ = (H) & 3; \
  char* dst_ = ldst + ((tt_ & 1) << 16) + (pos_ << 14); \
  const unsigned short* src_ = ((pos_ & 2) ? aptr : bptr) \
      + ((pos_ & 1) ? (size_t)128 * D_DIM : (size_t)0) + (size_t)tt_ * 64; \
  gload16(src_, dst_); \
  gload16(src_ + (size_t)64 * D_DIM, dst_ + 8192); \
} while (0)

#define MFMA8(AARR, KK) do { \
  _Pragma("unroll") \
  for (int mi = 0; mi < 4; ++mi) \
    acc[mi][0] = __builtin_amdgcn_mfma_f32_32x32x16_bf16(AARR[mi], bf0[KK], acc[mi][0], 0, 0, 0); \
  _Pragma("unroll") \
  for (int mi = 0; mi < 4; ++mi) \
    acc[mi][1] = __builtin_amdgcn_mfma_f32_32x32x16_bf16(AARR[mi], bf1[KK], acc[mi][1], 0, 0, 0); \
} while (0)

#define TILE2(T, HB, DOST, NVM, DONEXT) do { \
  char* curA_ = ldsAroot + (((T) & 1) << 16); \
  char* nxtA_ = ldsAroot + ((((T) + 1) & 1) << 16); \
  char* nxtB_ = ldsBroot + ((((T) + 1) & 1) << 16); \
  /* P_A: consume kk0,kk1; read kk2,kk3 */ \
  if ((DOST) > 0) STAGE((HB) + 0); \
  if ((DOST) > 1) STAGE((HB) + 1); \
  BAR; PRIO1; MFMA8(aK0, 0); MFMA8(aK1, 1); PRIO0; \
  aK2[0] = LDA32(curA_, 0, 2); aK2[1] = LDA32(curA_, 1, 2); \
  aK2[2] = LDA32(curA_, 2, 2); aK2[3] = LDA32(curA_, 3, 2); \
  aK3[0] = LDA32(curA_, 0, 3); aK3[1] = LDA32(curA_, 1, 3); \
  aK3[2] = LDA32(curA_, 2, 3); aK3[3] = LDA32(curA_, 3, 3); \
  BAR; \
  /* P_B: consume kk2,kk3; read next tile B(all) + A kk0,kk1 */ \
  if ((DOST) > 2) STAGE((HB) + 2); \
  if ((DOST) > 3) STAGE((HB) + 3); \
  if ((NVM) == 6) { VMC(6); } else if ((NVM) == 0) { VMC(0); } \
  BAR; PRIO1; MFMA8(aK2, 2); MFMA8(aK3, 3); PRIO0; \
  if (DONEXT) { \
    bf0[0] = LDB32(nxtB_, 0, 0); bf0[1] = LDB32(nxtB_, 0, 1); \
    bf0[2] = LDB32(nxtB_, 0, 2); bf0[3] = LDB32(nxtB_, 0, 3); \
    bf1[0] = LDB32(nxtB_, 1, 0); bf1[1] = LDB32(nxtB_, 1, 1); \
    bf1[2] = LDB32(nxtB_, 1, 2); bf1[3] = LDB32(nxtB_, 1, 3); \
    aK0[0] = LDA32(nxtA_, 0, 0); aK0[1] = LDA32(nxtA_, 1, 0); \
    aK0[2] = LDA32(nxtA_, 2, 0); aK0[3] = LDA32(nxtA_, 3, 0); \
    aK1[0] = LDA32(nxtA_, 0, 1); aK1[1] = LDA32(nxtA_, 1, 1); \
    aK1[2] = LDA32(nxtA_, 2, 1); aK1[3] = LDA32(nxtA_, 3, 1); \
  } \
  BAR; \
} while (0)

__global__ __launch_bounds__(512, 2) void gemm_lse_kernel(
    const unsigned short* __restrict__ xbf,   // [M_DIM][D_DIM]
    const unsigned short* __restrict__ wbf,   // [V_DIM][D_DIM]
    float* __restrict__ pMax,                 // [M_DIM][NSLOT]
    float* __restrict__ pSum,
    const unsigned int* __restrict__ bcnt,    // [2048]
    const unsigned int* __restrict__ ebuf,    // [2048][EBCAP]
    float* __restrict__ gout) {               // [M_DIM][K_TOP+1]
  __shared__ __align__(16) char lds[131072];

  // Locality mapping (round-5): round of 256 blocks = 16mt x 16vt square;
  // each XCD pinned to 2 vt columns.
  const int bid0 = blockIdx.x;
  const int mt = (bid0 >> 4) & 15;
  const int vt = ((bid0 >> 8) << 4) | (bid0 & 15);
  const int tid = threadIdx.x, lane = tid & 63, w = tid >> 6;
  const int wr = w >> 2, wc = w & 3;
  const int l31 = lane & 31, hi = lane >> 5;
  const int browB = (wc & 1) * 64;

  const int gcol = (((tid & 7) ^ ((tid >> 3) & 7)) << 3);
  const unsigned short* aptr = xbf + (size_t)(mt * 256 + (tid >> 3)) * D_DIM + gcol;
  const unsigned short* bptr = wbf + (size_t)(vt * 256 + (tid >> 3)) * D_DIM + gcol;
  char* ldst = lds + tid * 16;

  char* ldsAroot = lds + ((2 + wr) << 14);
  char* ldsBroot = lds + ((wc >> 1) << 14);

  f32x16 acc[4][2];
#pragma unroll
  for (int i = 0; i < 4; i++)
#pragma unroll
    for (int j = 0; j < 2; j++)
#pragma unroll
      for (int r = 0; r < 16; r++) acc[i][j][r] = 0.f;

  s16x8 aK0[4], aK1[4], aK2[4], aK3[4], bf0[4], bf1[4];

  // prologue: stage halves 0..6; pre-read tile-0 B(all) + A kk0,kk1
  STAGE(0); STAGE(1); STAGE(2); STAGE(3);
  VMC(4);
  STAGE(4); STAGE(5); STAGE(6);
  VMC(6);
  BAR;
  bf0[0] = LDB32(ldsBroot, 0, 0); bf0[1] = LDB32(ldsBroot, 0, 1);
  bf0[2] = LDB32(ldsBroot, 0, 2); bf0[3] = LDB32(ldsBroot, 0, 3);
  bf1[0] = LDB32(ldsBroot, 1, 0); bf1[1] = LDB32(ldsBroot, 1, 1);
  bf1[2] = LDB32(ldsBroot, 1, 2); bf1[3] = LDB32(ldsBroot, 1, 3);
  aK0[0] = LDA32(ldsAroot, 0, 0); aK0[1] = LDA32(ldsAroot, 1, 0);
  aK0[2] = LDA32(ldsAroot, 2, 0); aK0[3] = LDA32(ldsAroot, 3, 0);
  aK1[0] = LDA32(ldsAroot, 0, 1); aK1[1] = LDA32(ldsAroot, 1, 1);
  aK1[2] = LDA32(ldsAroot, 2, 1); aK1[3] = LDA32(ldsAroot, 3, 1);

  // main loop: 15 iters x 2 tiles; tail tiles 30, 31 (32 tiles of BK=64)
  for (int it = 0; it < 15; ++it) {
    TILE2(2 * it, 8 * it + 7, 4, 6, 1);
    TILE2(2 * it + 1, 8 * it + 11, 4, 6, 1);
  }
  TILE2(30, 127, 1, 0, 1);
  TILE2(31, 0, 0, 99, 0);

  // ---- epilogue A: per-row (max, sumexp) over this wave's 64-col slice ----
  const int slot = vt * 4 + wc;
#pragma unroll
  for (int mi = 0; mi < 4; mi++) {
#pragma unroll
    for (int r = 0; r < 16; r++) {
      float v0 = acc[mi][0][r], v1 = acc[mi][1][r];
      float mx = fmaxf(v0, v1);
      for (int s = 1; s < 32; s <<= 1) mx = fmaxf(mx, __shfl_xor(mx, s));
      float sm = __expf(v0 - mx) + __expf(v1 - mx);
      for (int s = 1; s < 32; s <<= 1) sm += __shfl_xor(sm, s);
      if (l31 == 0) {
        const int row = mt * 256 + wr * 128 + mi * 32 + (r & 3) + 8 * (r >> 2) + 4 * hi;
        pMax[row * NSLOT + slot] = mx;
        pSum[row * NSLOT + slot] = sm;
      }
    }
  }

  // ---- epilogue B: fused gather of requested logits via LDS round-trip ----
  // dump: 32 lanes write 32 consecutive f32 per row -> 2-way (free), no swizzle
  const int tile = (mt << 7) + vt;
  unsigned int cn = bcnt[tile];
  if (cn > EBCAP) cn = EBCAP;
  const unsigned int* elist = ebuf + tile * EBCAP;
  float* ldsf = (float*)lds;

  __syncthreads();
#pragma unroll
  for (int half = 0; half < 2; ++half) {
    if (wr == half) {
#pragma unroll
      for (int mi = 0; mi < 4; mi++)
#pragma unroll
        for (int ni = 0; ni < 2; ni++)
#pragma unroll
          for (int r = 0; r < 16; r++)
            ldsf[(mi * 32 + (r & 3) + 8 * (r >> 2) + 4 * hi) * 256 +
                 wc * 64 + ni * 32 + l31] = acc[mi][ni][r];
    }
    __syncthreads();
    for (unsigned int e = tid; e < cn; e += 512) {
      unsigned int u = elist[e];
      int r = (u >> 8) & 255;
      if ((r >> 7) == half) {
        int c = u & 255, k = u >> 16;
        gout[(mt * 256 + r) * (K_TOP + 1) + k] = ldsf[(r & 127) * 256 + c];
      }
    }
    __syncthreads();
  }
}

// ---------- final: lse merge + CE + KD, atomic into scalar ----------
__global__ __launch_bounds__(256) void reduce_kernel(
    const float* __restrict__ pMax, const float* __restrict__ pSum,
    const float* __restrict__ gout, const float* __restrict__ t_lp,
    const int* __restrict__ t_mask, float* __restrict__ out) {
  const int tid = threadIdx.x, lane = tid & 63, w = tid >> 6;
  const int m = blockIdx.x * 4 + w;

  float msl[8], ssl[8];
  float M = -1e30f;
#pragma unroll
  for (int j = 0; j < 8; j++) {
    msl[j] = pMax[m * NSLOT + lane + j * 64];
    ssl[j] = pSum[m * NSLOT + lane + j * 64];
    M = fmaxf(M, msl[j]);
  }
  for (int s = 1; s < 64; s <<= 1) M = fmaxf(M, __shfl_xor(M, s));
  float S = 0.f;
#pragma unroll
  for (int j = 0; j < 8; j++) S += ssl[j] * __expf(msl[j] - M);
  for (int s = 1; s < 64; s <<= 1) S += __shfl_xor(S, s);
  const float lse = M + logf(S);

  const int n = m & (N_SEQ - 1);
  float ce = 0.f;
  if (n < N_SEQ - 1) ce = lse - gout[m * (K_TOP + 1) + K_TOP];

  const float g = gout[m * (K_TOP + 1) + lane];
  float gM = g;
  for (int s = 1; s < 64; s <<= 1) gM = fmaxf(gM, __shfl_xor(gM, s));
  float gE = __expf(g - gM);
  float gS = gE;
  for (int s = 1; s < 64; s <<= 1) gS += __shfl_xor(gS, s);
  const float lseK = gM + logf(gS);

  const float tl = t_lp[m * K_TOP + lane];
  const int mk = t_mask[m * K_TOP + lane];
  float kd = mk ? __expf(tl) * (tl - (g - lseK)) : 0.f;
  for (int s = 1; s < 64; s <<= 1) kd += __shfl_xor(kd, s);

  if (lane == 0) atomicAdd(out, 0.5f * kd + 0.5f * ce);
}

// ---------- launch ----------
extern "C" void kernel_launch(void* const* d_in, const int* in_sizes, int n_in,
                              void* d_out, int out_size, void* d_ws, size_t ws_size,
                              hipStream_t stream) {
  const float* x   = (const float*)d_in[0];   // [2,2048,2048]
  const float* Wm  = (const float*)d_in[1];   // [32768,2048]
  const int* tids  = (const int*)d_in[2];     // [2,2048,64]
  const float* tlp = (const float*)d_in[3];   // [2,2048,64]
  const int* tmask = (const int*)d_in[4];     // [2,2048,64]
  const int* tlab  = (const int*)d_in[5];     // [2,2048]
  float* out = (float*)d_out;

  char* ws = (char*)d_ws;
  unsigned short* wbf = (unsigned short*)ws;                                 // 128 MB
  unsigned short* xbf = (unsigned short*)(ws + (size_t)V_DIM * D_DIM * 2);   // 16 MB
  char* p = ws + (size_t)V_DIM * D_DIM * 2 + (size_t)M_DIM * D_DIM * 2;
  float* pMax = (float*)p;                       p += (size_t)M_DIM * NSLOT * 4;
  float* pSum = (float*)p;                       p += (size_t)M_DIM * NSLOT * 4;
  float* gout = (float*)p;                       p += (size_t)M_DIM * (K_TOP + 1) * 4;
  unsigned int* bcnt = (unsigned int*)p;         p += 2048 * 4;
  unsigned int* ebuf = (unsigned int*)p;         p += (size_t)2048 * EBCAP * 4;

  hipMemsetAsync(d_out, 0, sizeof(float), stream);
  hipMemsetAsync(bcnt, 0, 2048 * 4, stream);

  bin_kernel<<<(M_DIM * (K_TOP + 1) + 255) / 256, 256, 0, stream>>>(
      tids, tlab, bcnt, ebuf);

  cast_bf16_kernel<<<8192, 256, 0, stream>>>(
      (const float4*)Wm, (uint4*)wbf, (V_DIM * D_DIM) / 8,
      (const float4*)x, (uint4*)xbf, (M_DIM * D_DIM) / 8);

  gemm_lse_kernel<<<(M_DIM / 256) * (V_DIM / 256), 512, 0, stream>>>(
      xbf, wbf, pMax, pSum, bcnt, ebuf, gout);

  reduce_kernel<<<M_DIM / 4, 256, 0, stream>>>(pMax, pSum, gout, tlp, tmask, out);
}

// Round 8
// 663.711 us; speedup vs baseline: 2.0784x; 1.2432x over previous
//
#include <hip/hip_runtime.h>
#include <hip/hip_bf16.h>
#include <stdint.h>

typedef __attribute__((ext_vector_type(8))) short s16x8;
typedef __attribute__((ext_vector_type(4))) float f32x4;

#define D_DIM 2048
#define V_DIM 32768
#define M_DIM 4096
#define N_SEQ 2048
#define K_TOP 64
#define NSLOT 512   // 128 v-tiles * 4 wc
#define EBCAP 512   // entries per 256x256 tile (avg ~130)

// ---------- helpers ----------
static __device__ __forceinline__ float bf2f(unsigned short u) {
  union { unsigned int i; float f; } v; v.i = ((unsigned int)u) << 16; return v.f;
}
static __device__ __forceinline__ unsigned int pack2_bf16(float lo, float hi) {
  unsigned int ul = __float_as_uint(lo), uh = __float_as_uint(hi);
  ul = (ul + 0x7FFFu + ((ul >> 16) & 1u)) >> 16;        // RNE
  uh = (uh + 0x7FFFu + ((uh >> 16) & 1u)) >> 16;
  return ul | (uh << 16);
}
typedef __attribute__((address_space(3))) unsigned int lds_u32_t;
typedef const __attribute__((address_space(1))) unsigned int glb_u32_t;
static __device__ __forceinline__ void gload16(const void* g, void* l) {
  __builtin_amdgcn_global_load_lds((glb_u32_t*)g, (lds_u32_t*)l, 16, 0, 0);
}

// ---------- cast f32 -> bf16 (both tensors, one launch) ----------
__global__ void cast_bf16_kernel(const float4* __restrict__ inA, uint4* __restrict__ outA, int nA8,
                                 const float4* __restrict__ inB, uint4* __restrict__ outB, int nB8) {
  int i = blockIdx.x * blockDim.x + threadIdx.x;
  int stride = gridDim.x * blockDim.x;
  int tot = nA8 + nB8;
  for (; i < tot; i += stride) {
    const float4* in = (i < nA8) ? inA : inB;
    uint4* out = (i < nA8) ? outA : outB;
    int j = (i < nA8) ? i : i - nA8;
    float4 a = in[2 * j], b = in[2 * j + 1];
    uint4 r;
    r.x = pack2_bf16(a.x, a.y);
    r.y = pack2_bf16(a.z, a.w);
    r.z = pack2_bf16(b.x, b.y);
    r.w = pack2_bf16(b.z, b.w);
    out[j] = r;
  }
}

// ---------- binning: (m, id) -> per-(mt,vt)-tile entry lists ----------
__global__ __launch_bounds__(256) void bin_kernel(
    const int* __restrict__ tids, const int* __restrict__ tlab,
    unsigned int* __restrict__ cnt, unsigned int* __restrict__ ebuf) {
  int idx = blockIdx.x * 256 + threadIdx.x;
  if (idx >= M_DIM * (K_TOP + 1)) return;
  int m = idx / (K_TOP + 1), k = idx - m * (K_TOP + 1);
  int id;
  if (k < K_TOP) id = tids[m * K_TOP + k];
  else {
    int n = m & (N_SEQ - 1);
    if (n == N_SEQ - 1) return;   // no gold for last position
    id = tlab[m + 1];
  }
  int tile = ((m >> 8) << 7) + (id >> 8);   // mt*128 + vt
  unsigned int pos = atomicAdd(&cnt[tile], 1u);
  if (pos < EBCAP)
    ebuf[tile * EBCAP + pos] =
        ((unsigned int)k << 16) | ((unsigned int)(m & 255) << 8) | (unsigned int)(id & 255);
}

// ---------- 256x256 GEMM, 16x16x32 MFMA, 1 barrier per phase ----------
// 8 waves (2M x 4N), BK=64, 128KB LDS dbuf, halves pos0/1=B, pos2/3=A.
// Granule swizzle g ^= row&7 (pre-applied on global src) -> 0 conflicts (verified r2-5).
// Segments per tile T (1 barrier each):
//  s1: BAR; stage (T+2)p0; MFMA mi0-1; read A mi2,3
//  s2: BAR; stage (T+2)p1; MFMA mi2-3; read A mi4,5
//  s3: BAR;                MFMA mi4-5; read A mi6,7; VMC(4)
//  s4: BAR; stage (T+2)p2,p3; MFMA mi6-7; read B(T+1)+A(T+1)mi0,1
// Liveness: every staged slot's last read is >=1 barrier before the stage;
// VMC(4) at s3 (2 loads/half) guarantees halves <=4T+7 (= tile T+1) landed.

#define BAR do { __builtin_amdgcn_s_barrier(); asm volatile("" ::: "memory"); } while (0)
#define VMC(N) asm volatile("s_waitcnt vmcnt(" #N ")" ::: "memory")
#define PRIO1 __builtin_amdgcn_s_setprio(1)
#define PRIO0 __builtin_amdgcn_s_setprio(0)

#define LDFRAG(BASE, R, G) \
  (*(const s16x8*)((BASE) + (R) * 128 + ((((G)) ^ ((R) & 7)) << 4)))
#define LDA(BASE, MI, KS) LDFRAG(BASE, (MI) * 16 + fr, (KS) * 4 + kqg)
#define LDB(BASE, NI, KS) LDFRAG(BASE, brow + (NI) * 16 + fr, (KS) * 4 + kqg)

#define STAGE(H) do { \
  int tt_ = (H) >> 2, pos_ = (H) & 3; \
  char* dst_ = ldst + ((tt_ & 1) << 16) + (pos_ << 14); \
  const unsigned short* src_ = ((pos_ & 2) ? aptr : bptr) \
      + ((pos_ & 1) ? (size_t)128 * D_DIM : (size_t)0) + (size_t)tt_ * 64; \
  gload16(src_, dst_); \
  gload16(src_ + (size_t)64 * D_DIM, dst_ + 8192); \
} while (0)

// dependent reuse distance = 8 MFMAs (k0 sweep then k1 sweep)
#define MFMA_Q(M0, U) do { \
  _Pragma("unroll") \
  for (int ni = 0; ni < 4; ++ni) \
    acc[M0][ni] = __builtin_amdgcn_mfma_f32_16x16x32_bf16(U[0][0], bfrag[ni][0], acc[M0][ni], 0, 0, 0); \
  _Pragma("unroll") \
  for (int ni = 0; ni < 4; ++ni) \
    acc[(M0) + 1][ni] = __builtin_amdgcn_mfma_f32_16x16x32_bf16(U[1][0], bfrag[ni][0], acc[(M0) + 1][ni], 0, 0, 0); \
  _Pragma("unroll") \
  for (int ni = 0; ni < 4; ++ni) \
    acc[M0][ni] = __builtin_amdgcn_mfma_f32_16x16x32_bf16(U[0][1], bfrag[ni][1], acc[M0][ni], 0, 0, 0); \
  _Pragma("unroll") \
  for (int ni = 0; ni < 4; ++ni) \
    acc[(M0) + 1][ni] = __builtin_amdgcn_mfma_f32_16x16x32_bf16(U[1][1], bfrag[ni][1], acc[(M0) + 1][ni], 0, 0, 0); \
} while (0)

// Entering invariant: bfrag = B(T), aq = A-q0(T) (read in s4 of T-1 / prologue).
#define TILE1B(T, DOST, NVM, DONEXT) do { \
  char* curA_ = ldsAroot + (((T) & 1) << 16); \
  char* nxtA_ = ldsAroot + ((((T) + 1) & 1) << 16); \
  char* nxtB_ = ldsBroot + ((((T) + 1) & 1) << 16); \
  /* s1 */ \
  BAR; \
  if (DOST) STAGE(4 * (T) + 8); \
  PRIO1; MFMA_Q(0, aq); PRIO0; \
  aqn[0][0] = LDA(curA_, 2, 0); aqn[0][1] = LDA(curA_, 2, 1); \
  aqn[1][0] = LDA(curA_, 3, 0); aqn[1][1] = LDA(curA_, 3, 1); \
  /* s2 */ \
  BAR; \
  if (DOST) STAGE(4 * (T) + 9); \
  PRIO1; MFMA_Q(2, aqn); PRIO0; \
  aq[0][0] = LDA(curA_, 4, 0); aq[0][1] = LDA(curA_, 4, 1); \
  aq[1][0] = LDA(curA_, 5, 0); aq[1][1] = LDA(curA_, 5, 1); \
  /* s3 */ \
  BAR; \
  PRIO1; MFMA_Q(4, aq); PRIO0; \
  aqn[0][0] = LDA(curA_, 6, 0); aqn[0][1] = LDA(curA_, 6, 1); \
  aqn[1][0] = LDA(curA_, 7, 0); aqn[1][1] = LDA(curA_, 7, 1); \
  if ((NVM) == 4) { VMC(4); } else if ((NVM) == 0) { VMC(0); } \
  /* s4 */ \
  BAR; \
  if (DOST) { STAGE(4 * (T) + 10); STAGE(4 * (T) + 11); } \
  PRIO1; MFMA_Q(6, aqn); PRIO0; \
  if (DONEXT) { \
    _Pragma("unroll") \
    for (int ni = 0; ni < 4; ++ni) { \
      bfrag[ni][0] = LDB(nxtB_, ni, 0); bfrag[ni][1] = LDB(nxtB_, ni, 1); } \
    aq[0][0] = LDA(nxtA_, 0, 0); aq[0][1] = LDA(nxtA_, 0, 1); \
    aq[1][0] = LDA(nxtA_, 1, 0); aq[1][1] = LDA(nxtA_, 1, 1); \
  } \
} while (0)

__global__ __launch_bounds__(512, 2) void gemm_lse_kernel(
    const unsigned short* __restrict__ xbf,   // [M_DIM][D_DIM]
    const unsigned short* __restrict__ wbf,   // [V_DIM][D_DIM]
    float* __restrict__ pMax,                 // [M_DIM][NSLOT]
    float* __restrict__ pSum,
    const unsigned int* __restrict__ bcnt,    // [2048]
    const unsigned int* __restrict__ ebuf,    // [2048][EBCAP]
    float* __restrict__ gout) {               // [M_DIM][K_TOP+1]
  __shared__ __align__(16) char lds[131072];

  // Locality mapping (round-5): round of 256 blocks = 16mt x 16vt square;
  // each XCD pinned to 2 vt columns.
  const int bid0 = blockIdx.x;
  const int mt = (bid0 >> 4) & 15;
  const int vt = ((bid0 >> 8) << 4) | (bid0 & 15);
  const int tid = threadIdx.x, lane = tid & 63, w = tid >> 6;
  const int wr = w >> 2, wc = w & 3;
  const int fr = lane & 15, kqg = lane >> 4;
  const int brow = (wc & 1) * 64;

  const int gcol = (((tid & 7) ^ ((tid >> 3) & 7)) << 3);
  const unsigned short* aptr = xbf + (size_t)(mt * 256 + (tid >> 3)) * D_DIM + gcol;
  const unsigned short* bptr = wbf + (size_t)(vt * 256 + (tid >> 3)) * D_DIM + gcol;
  char* ldst = lds + tid * 16;

  char* ldsAroot = lds + ((2 + wr) << 14);
  char* ldsBroot = lds + ((wc >> 1) << 14);

  f32x4 acc[8][4];
#pragma unroll
  for (int i = 0; i < 8; i++)
#pragma unroll
    for (int j = 0; j < 4; j++) acc[i][j] = (f32x4){0.f, 0.f, 0.f, 0.f};

  s16x8 bfrag[4][2], aq[2][2], aqn[2][2];

  // prologue: stage tiles 0 and 1 fully (halves 0..7), drain, pre-read tile0
  STAGE(0); STAGE(1); STAGE(2); STAGE(3);
  VMC(4);
  STAGE(4); STAGE(5); STAGE(6); STAGE(7);
  VMC(0);
  BAR;
#pragma unroll
  for (int ni = 0; ni < 4; ++ni) {
    bfrag[ni][0] = LDB(ldsBroot, ni, 0); bfrag[ni][1] = LDB(ldsBroot, ni, 1);
  }
  aq[0][0] = LDA(ldsAroot, 0, 0); aq[0][1] = LDA(ldsAroot, 0, 1);
  aq[1][0] = LDA(ldsAroot, 1, 0); aq[1][1] = LDA(ldsAroot, 1, 1);

  // main loop: tiles 0..29 (stage T+2), tail tiles 30, 31
  for (int it = 0; it < 15; ++it) {
    TILE1B(2 * it, 1, 4, 1);
    TILE1B(2 * it + 1, 1, 4, 1);
  }
  TILE1B(30, 0, 0, 1);
  TILE1B(31, 0, 99, 0);

  // ---- epilogue A: per-row (max, sumexp) over this wave's 64-col slice ----
  const int slot = vt * 4 + wc;
#pragma unroll
  for (int mi = 0; mi < 8; mi++) {
#pragma unroll
    for (int j = 0; j < 4; j++) {
      const int row = mt * 256 + wr * 128 + mi * 16 + kqg * 4 + j;
      float v0 = acc[mi][0][j], v1 = acc[mi][1][j];
      float v2 = acc[mi][2][j], v3 = acc[mi][3][j];
      float mx = fmaxf(fmaxf(v0, v1), fmaxf(v2, v3));
      for (int s = 1; s < 16; s <<= 1) mx = fmaxf(mx, __shfl_xor(mx, s));
      float sm = __expf(v0 - mx) + __expf(v1 - mx) +
                 __expf(v2 - mx) + __expf(v3 - mx);
      for (int s = 1; s < 16; s <<= 1) sm += __shfl_xor(sm, s);
      if (fr == 0) {
        pMax[row * NSLOT + slot] = mx;
        pSum[row * NSLOT + slot] = sm;
      }
    }
  }

  // ---- epilogue B: fused gather of requested logits via LDS round-trip ----
  // col swizzle c ^= ((r>>2)&1)<<4 spreads the 4 kqg-rows across banks (2-way = free)
  const int tile = (mt << 7) + vt;
  unsigned int cn = bcnt[tile];
  if (cn > EBCAP) cn = EBCAP;
  const unsigned int* elist = ebuf + tile * EBCAP;
  float* ldsf = (float*)lds;

  __syncthreads();
#pragma unroll
  for (int half = 0; half < 2; ++half) {
    if (wr == half) {
#pragma unroll
      for (int mi = 0; mi < 8; mi++) {
        const int r0 = mi * 16 + kqg * 4;
        const int cs = (kqg & 1) << 4;
#pragma unroll
        for (int ni = 0; ni < 4; ni++) {
          const int c0 = (wc * 64 + ni * 16 + fr) ^ cs;
#pragma unroll
          for (int j = 0; j < 4; j++)
            ldsf[(r0 + j) * 256 + c0] = acc[mi][ni][j];
        }
      }
    }
    __syncthreads();
    for (unsigned int e = tid; e < cn; e += 512) {
      unsigned int u = elist[e];
      int r = (u >> 8) & 255;
      if ((r >> 7) == half) {
        int c = u & 255, k = u >> 16;
        int rl = r & 127;
        gout[(mt * 256 + r) * (K_TOP + 1) + k] = ldsf[rl * 256 + (c ^ (((rl >> 2) & 1) << 4))];
      }
    }
    __syncthreads();
  }
}

// ---------- final: lse merge + CE + KD, atomic into scalar ----------
__global__ __launch_bounds__(256) void reduce_kernel(
    const float* __restrict__ pMax, const float* __restrict__ pSum,
    const float* __restrict__ gout, const float* __restrict__ t_lp,
    const int* __restrict__ t_mask, float* __restrict__ out) {
  const int tid = threadIdx.x, lane = tid & 63, w = tid >> 6;
  const int m = blockIdx.x * 4 + w;

  float msl[8], ssl[8];
  float M = -1e30f;
#pragma unroll
  for (int j = 0; j < 8; j++) {
    msl[j] = pMax[m * NSLOT + lane + j * 64];
    ssl[j] = pSum[m * NSLOT + lane + j * 64];
    M = fmaxf(M, msl[j]);
  }
  for (int s = 1; s < 64; s <<= 1) M = fmaxf(M, __shfl_xor(M, s));
  float S = 0.f;
#pragma unroll
  for (int j = 0; j < 8; j++) S += ssl[j] * __expf(msl[j] - M);
  for (int s = 1; s < 64; s <<= 1) S += __shfl_xor(S, s);
  const float lse = M + logf(S);

  const int n = m & (N_SEQ - 1);
  float ce = 0.f;
  if (n < N_SEQ - 1) ce = lse - gout[m * (K_TOP + 1) + K_TOP];

  const float g = gout[m * (K_TOP + 1) + lane];
  float gM = g;
  for (int s = 1; s < 64; s <<= 1) gM = fmaxf(gM, __shfl_xor(gM, s));
  float gE = __expf(g - gM);
  float gS = gE;
  for (int s = 1; s < 64; s <<= 1) gS += __shfl_xor(gS, s);
  const float lseK = gM + logf(gS);

  const float tl = t_lp[m * K_TOP + lane];
  const int mk = t_mask[m * K_TOP + lane];
  float kd = mk ? __expf(tl) * (tl - (g - lseK)) : 0.f;
  for (int s = 1; s < 64; s <<= 1) kd += __shfl_xor(kd, s);

  if (lane == 0) atomicAdd(out, 0.5f * kd + 0.5f * ce);
}

// ---------- launch ----------
extern "C" void kernel_launch(void* const* d_in, const int* in_sizes, int n_in,
                              void* d_out, int out_size, void* d_ws, size_t ws_size,
                              hipStream_t stream) {
  const float* x   = (const float*)d_in[0];   // [2,2048,2048]
  const float* Wm  = (const float*)d_in[1];   // [32768,2048]
  const int* tids  = (const int*)d_in[2];     // [2,2048,64]
  const float* tlp = (const float*)d_in[3];   // [2,2048,64]
  const int* tmask = (const int*)d_in[4];     // [2,2048,64]
  const int* tlab  = (const int*)d_in[5];     // [2,2048]
  float* out = (float*)d_out;

  char* ws = (char*)d_ws;
  unsigned short* wbf = (unsigned short*)ws;                                 // 128 MB
  unsigned short* xbf = (unsigned short*)(ws + (size_t)V_DIM * D_DIM * 2);   // 16 MB
  char* p = ws + (size_t)V_DIM * D_DIM * 2 + (size_t)M_DIM * D_DIM * 2;
  float* pMax = (float*)p;                       p += (size_t)M_DIM * NSLOT * 4;
  float* pSum = (float*)p;                       p += (size_t)M_DIM * NSLOT * 4;
  float* gout = (float*)p;                       p += (size_t)M_DIM * (K_TOP + 1) * 4;
  unsigned int* bcnt = (unsigned int*)p;         p += 2048 * 4;
  unsigned int* ebuf = (unsigned int*)p;         p += (size_t)2048 * EBCAP * 4;

  hipMemsetAsync(d_out, 0, sizeof(float), stream);
  hipMemsetAsync(bcnt, 0, 2048 * 4, stream);

  bin_kernel<<<(M_DIM * (K_TOP + 1) + 255) / 256, 256, 0, stream>>>(
      tids, tlab, bcnt, ebuf);

  cast_bf16_kernel<<<8192, 256, 0, stream>>>(
      (const float4*)Wm, (uint4*)wbf, (V_DIM * D_DIM) / 8,
      (const float4*)x, (uint4*)xbf, (M_DIM * D_DIM) / 8);

  gemm_lse_kernel<<<(M_DIM / 256) * (V_DIM / 256), 512, 0, stream>>>(
      xbf, wbf, pMax, pSum, bcnt, ebuf, gout);

  reduce_kernel<<<M_DIM / 4, 256, 0, stream>>>(pMax, pSum, gout, tlp, tmask, out);
}